// Round 3
// baseline (1431.421 us; speedup 1.0000x reference)
//
#include <hip/hip_runtime.h>

// Problem constants (from reference)
#define VOCAB 32000
#define HALF  16000           // half a vocab row staged per block (62.5 KB LDS)
#define NNZ   801
#define NROWS 8192            // B*T = 4*2048
#define TPB   512             // 8 waves; LDS (62.5KB) limits to 2 blocks/CU -> 16 waves/CU

// d_ws float layout: [0,NROWS) sum_val | [NROWS,3*NROWS) gv per half | [3*NROWS,4*NROWS) ml term
__global__ __launch_bounds__(TPB) void wordsmooth_main(
        const float* __restrict__ logp,        // [NROWS, VOCAB]
        const float* __restrict__ mask,        // [NROWS]
        const float* __restrict__ sim_values,  // [VOCAB, NNZ]
        const float* __restrict__ idf_values,  // [VOCAB, NNZ]
        const int*   __restrict__ target,      // [NROWS]
        const int*   __restrict__ sim_cols,    // [VOCAB, NNZ]
        float*       __restrict__ ws)
{
    __shared__ __align__(16) float lds[HALF];
    __shared__ float red[16];

    const int row  = blockIdx.x >> 1;      // 0..8191
    const int half = blockIdx.x & 1;       // 0 or 1
    const int tid  = threadIdx.x;
    const int lo   = half * HALF;

    // ---- stage half of this row's logp into LDS, fully coalesced float4 ----
    // byte offset of (row*VOCAB + lo) is row*128000 + half*64000 -> 16B aligned
    const float4* __restrict__ src4 = (const float4*)(logp + (size_t)row * VOCAB + lo);
    float4* dst4 = (float4*)lds;
    #pragma unroll
    for (int i = 0; i < 8; ++i) {          // 4000 float4s, 512 threads -> 7 full + partial
        int idx = tid + i * TPB;
        if (idx < HALF / 4) dst4[idx] = src4[idx];
    }
    __syncthreads();

    // ---- stream the sparse row, gather from LDS ----
    const int trow = target[row];
    const size_t base = (size_t)trow * NNZ;
    const float* __restrict__ sv_p = sim_values + base;
    const float* __restrict__ iv_p = idf_values + base;
    const int*   __restrict__ sc_p = sim_cols   + base;

    // x = (sv - 1 - 0.8*iv) * 1.25 = 1.25*sv - 1.25 - iv ; val = exp(exp(x)*1.25)
    float s_v = 0.0f, s_gv = 0.0f;
    for (int j = tid; j < NNZ; j += TPB) {  // 2 iterations (512 + 289)
        float sv = sv_p[j];
        float iv = iv_p[j];
        int   c  = sc_p[j];
        float x   = __fmaf_rn(1.25f, sv, -1.25f) - iv;
        float val = __expf(__expf(x) * 1.25f);
        s_v += val;
        int cl = c - lo;
        if ((unsigned)cl < (unsigned)HALF) s_gv += lds[cl] * val;
    }

    // ---- block reduction (8 waves) ----
    #pragma unroll
    for (int off = 32; off > 0; off >>= 1) {
        s_v  += __shfl_down(s_v,  off, 64);
        s_gv += __shfl_down(s_gv, off, 64);
    }
    const int wv = tid >> 6, ln = tid & 63;
    if (ln == 0) { red[wv] = s_v; red[8 + wv] = s_gv; }
    __syncthreads();
    if (tid == 0) {
        float tv = 0.0f, tg = 0.0f;
        #pragma unroll
        for (int w = 0; w < 8; ++w) { tv += red[w]; tg += red[8 + w]; }
        ws[NROWS + half * NROWS + row] = tg;      // gv for this half
        if (half == 0) ws[row] = tv;              // sum of vals (full, independent of half)
        int cl = trow - lo;                        // ml term: owner half writes it
        if ((unsigned)cl < (unsigned)HALF) ws[3 * NROWS + row] = -lds[cl] * mask[row];
    }
}

__global__ __launch_bounds__(256) void wordsmooth_finalize(
        const float* __restrict__ ws, const float* __restrict__ mask,
        float* __restrict__ out)
{
    double sm = 0.0, ml = 0.0, dn = 0.0;
    for (int r = threadIdx.x; r < NROWS; r += 256) {
        float svv = ws[r];
        float gv  = ws[NROWS + r] + ws[2 * NROWS + r];
        sm += (double)(-gv / svv);
        ml += (double)ws[3 * NROWS + r];
        dn += (double)mask[r];
    }
    #pragma unroll
    for (int off = 32; off > 0; off >>= 1) {
        sm += __shfl_down(sm, off, 64);
        ml += __shfl_down(ml, off, 64);
        dn += __shfl_down(dn, off, 64);
    }
    __shared__ double sh[3][4];
    const int ln = threadIdx.x & 63, wv = threadIdx.x >> 6;
    if (ln == 0) { sh[0][wv] = sm; sh[1][wv] = ml; sh[2][wv] = dn; }
    __syncthreads();
    if (threadIdx.x == 0) {
        double S = 0.0, M = 0.0, D = 0.0;
        #pragma unroll
        for (int w = 0; w < 4; ++w) { S += sh[0][w]; M += sh[1][w]; D += sh[2][w]; }
        out[0] = (float)((0.7 * S + 0.3 * M) / D);
    }
}

extern "C" void kernel_launch(void* const* d_in, const int* in_sizes, int n_in,
                              void* d_out, int out_size, void* d_ws, size_t ws_size,
                              hipStream_t stream) {
    const float* logp       = (const float*)d_in[0];
    const float* mask       = (const float*)d_in[1];
    const float* sim_values = (const float*)d_in[2];
    const float* idf_values = (const float*)d_in[3];
    const int*   target     = (const int*)d_in[4];
    const int*   sim_cols   = (const int*)d_in[5];
    float* out = (float*)d_out;
    float* ws  = (float*)d_ws;   // 4*NROWS floats = 128 KB, every slot overwritten each call

    wordsmooth_main<<<dim3(NROWS * 2), dim3(TPB), 0, stream>>>(
        logp, mask, sim_values, idf_values, target, sim_cols, ws);
    wordsmooth_finalize<<<dim3(1), dim3(256), 0, stream>>>(ws, mask, out);
}